// Round 3
// baseline (1564.879 us; speedup 1.0000x reference)
//
#include <hip/hip_runtime.h>
#include <hip/hip_bf16.h>

#define B_  16
#define C_  1024
#define NP_ 512
#define DM_ 512
#define H_  8
#define D_  64
#define BC_ 16384

#define BM 128
#define BN 128
#define BKT 16
#define LDT 132
#define NEG_INF (-3.402823466e38f)

// ---- fp32 tile GEMM core: acc += A(row-major, M x K) * B(row-major, N x K)^T ----
__device__ __forceinline__ void sgemm_tile(const float* __restrict__ A,
                                           const float* __restrict__ Bm,
                                           int Kk, int lda, int ldb,
                                           int row0, int col0,
                                           float* __restrict__ As, float* __restrict__ Bs,
                                           float (&acc)[8][8])
{
    const int tid = threadIdx.x;
    const int ty4 = (tid >> 4) << 2;
    const int tx4 = (tid & 15) << 2;
    for (int k0 = 0; k0 < Kk; k0 += BKT) {
#pragma unroll
        for (int v = 0; v < 2; ++v) {
            const int i = tid + v * 256;
            const int m = i >> 2;
            const int kq = (i & 3) << 2;
            const float4 av = *(const float4*)(A + (size_t)(row0 + m) * lda + k0 + kq);
            As[(kq + 0) * LDT + m] = av.x;
            As[(kq + 1) * LDT + m] = av.y;
            As[(kq + 2) * LDT + m] = av.z;
            As[(kq + 3) * LDT + m] = av.w;
            const float4 bv = *(const float4*)(Bm + (size_t)(col0 + m) * ldb + k0 + kq);
            Bs[(kq + 0) * LDT + m] = bv.x;
            Bs[(kq + 1) * LDT + m] = bv.y;
            Bs[(kq + 2) * LDT + m] = bv.z;
            Bs[(kq + 3) * LDT + m] = bv.w;
        }
        __syncthreads();
#pragma unroll
        for (int kk = 0; kk < BKT; ++kk) {
            const float* Ar = As + kk * LDT;
            const float* Br = Bs + kk * LDT;
            const float4 a0 = *(const float4*)(Ar + ty4);
            const float4 a1 = *(const float4*)(Ar + 64 + ty4);
            const float4 b0 = *(const float4*)(Br + tx4);
            const float4 b1 = *(const float4*)(Br + 64 + tx4);
            const float a[8]  = {a0.x, a0.y, a0.z, a0.w, a1.x, a1.y, a1.z, a1.w};
            const float bb[8] = {b0.x, b0.y, b0.z, b0.w, b1.x, b1.y, b1.z, b1.w};
#pragma unroll
            for (int ii = 0; ii < 8; ++ii)
#pragma unroll
                for (int jj = 0; jj < 8; ++jj)
                    acc[ii][jj] = fmaf(a[ii], bb[jj], acc[ii][jj]);
        }
        __syncthreads();
    }
}

__device__ __forceinline__ int row_of(int r, int ty4) {
    return (r < 4) ? (ty4 + r) : (64 + ty4 + r - 4);
}

// ---- kernel 1: Q/K/V projections for a chunk of nb batches ----
__global__ __launch_bounds__(256) void qkv_gemm(const float* __restrict__ Mi,
    const float* __restrict__ Wq, const float* __restrict__ Wk, const float* __restrict__ Wv,
    float* __restrict__ Q, float* __restrict__ K, float* __restrict__ V)
{
    __shared__ float smem[2 * BKT * LDT];
    const int z = blockIdx.z;
    const float* W = (z == 0) ? Wq : (z == 1) ? Wk : Wv;
    float* C = (z == 0) ? Q : (z == 1) ? K : V;
    const int row0 = blockIdx.x * BM, col0 = blockIdx.y * BN;
    float acc[8][8] = {};
    sgemm_tile(Mi, W, NP_, NP_, NP_, row0, col0, smem, smem + BKT * LDT, acc);
    const int ty4 = (threadIdx.x >> 4) << 2;
    const int tx4 = (threadIdx.x & 15) << 2;
#pragma unroll
    for (int r = 0; r < 8; ++r) {
        const int gr = row0 + row_of(r, ty4);
        *(float4*)(C + (size_t)gr * DM_ + col0 + tx4) =
            make_float4(acc[r][0], acc[r][1], acc[r][2], acc[r][3]);
        *(float4*)(C + (size_t)gr * DM_ + col0 + 64 + tx4) =
            make_float4(acc[r][4], acc[r][5], acc[r][6], acc[r][7]);
    }
}

// ---- kernel 2: per-(bl,h) scores S = (QK^T)*scale, chunk-local ----
__global__ __launch_bounds__(256) void score_gemm(const float* __restrict__ Q,
    const float* __restrict__ K, float* __restrict__ S)
{
    __shared__ float smem[2 * BKT * LDT];
    const int z = blockIdx.z;
    const int h = z & 7, bl = z >> 3;
    const float* A  = Q + (size_t)bl * C_ * DM_ + h * D_;
    const float* Bp = K + (size_t)bl * C_ * DM_ + h * D_;
    float* C = S + (size_t)z * C_ * C_;
    const int row0 = blockIdx.x * BM, col0 = blockIdx.y * BN;
    float acc[8][8] = {};
    sgemm_tile(A, Bp, D_, DM_, DM_, row0, col0, smem, smem + BKT * LDT, acc);
    const int ty4 = (threadIdx.x >> 4) << 2;
    const int tx4 = (threadIdx.x & 15) << 2;
#pragma unroll
    for (int r = 0; r < 8; ++r) {
        const int gr = row0 + row_of(r, ty4);
        *(float4*)(C + (size_t)gr * C_ + col0 + tx4) =
            make_float4(acc[r][0] * 0.125f, acc[r][1] * 0.125f, acc[r][2] * 0.125f, acc[r][3] * 0.125f);
        *(float4*)(C + (size_t)gr * C_ + col0 + 64 + tx4) =
            make_float4(acc[r][4] * 0.125f, acc[r][5] * 0.125f, acc[r][6] * 0.125f, acc[r][7] * 0.125f);
    }
}

// ---- wave-level iterative top-16 (argmax w/ min-index tie-break, matches lax.top_k) ----
__device__ __forceinline__ void wave_topk16(float (&v)[16], const int lane, float& selv, int& selj)
{
    selv = NEG_INF; selj = 0;
#pragma unroll
    for (int it = 0; it < 16; ++it) {
        float bv = v[0]; int bj = lane;
#pragma unroll
        for (int r = 1; r < 16; ++r) {
            const int jj = lane + r * 64;
            if (v[r] > bv) { bv = v[r]; bj = jj; }
        }
#pragma unroll
        for (int off = 32; off >= 1; off >>= 1) {
            const float ov = __shfl_xor(bv, off);
            const int   oj = __shfl_xor(bj, off);
            if (ov > bv || (ov == bv && oj < bj)) { bv = ov; bj = oj; }
        }
        if (lane == it) { selv = bv; selj = bj; }
#pragma unroll
        for (int r = 0; r < 16; ++r)
            if (bj == lane + r * 64) v[r] = NEG_INF;
    }
}

// ---- kernel 3: per-row topk + softmax + sparse AV + A output (fp32 A) ----
// S, V, O are chunk-local; O aliases the Q buffer (Q fully consumed by score_gemm).
__global__ __launch_bounds__(256) void topk_attn(const float* __restrict__ S,
    const float* __restrict__ V, float* __restrict__ O,
    float* __restrict__ Aout, int b0)
{
    __shared__ float pavg[4][1024];
    __shared__ float wts[8][16];
    __shared__ int   jidx[8][16];
    __shared__ int   aidx[16];
    __shared__ float arow[1024];

    const int tid = threadIdx.x, lane = tid & 63, w = tid >> 6;
    const int rb = blockIdx.x, bl = rb >> 10, i = rb & 1023;
    const int b = b0 + bl;

    float v1[16], v2[16];
    const float* r1 = S + ((size_t)(bl * 8 + w) * C_ + i) * C_;
    const float* r2 = S + ((size_t)(bl * 8 + w + 4) * C_ + i) * C_;
#pragma unroll
    for (int r = 0; r < 16; ++r) { v1[r] = r1[lane + r * 64]; v2[r] = r2[lane + r * 64]; }
#pragma unroll
    for (int r = 0; r < 16; ++r) pavg[w][lane + r * 64] = v1[r] + v2[r];
#pragma unroll
    for (int c = 0; c < 4; ++c) arow[tid + 256 * c] = 0.0f;
    __syncthreads();

    {
        float selv; int selj;
        wave_topk16(v1, lane, selv, selj);
        const float v0 = __shfl(selv, 0);
        float e = (lane < 16) ? expf(selv - v0) : 0.0f;
        float Z = e;
#pragma unroll
        for (int off = 32; off >= 1; off >>= 1) Z += __shfl_xor(Z, off);
        if (lane < 16) { wts[w][lane] = e / Z; jidx[w][lane] = selj; }
    }
    {
        float selv; int selj;
        wave_topk16(v2, lane, selv, selj);
        const float v0 = __shfl(selv, 0);
        float e = (lane < 16) ? expf(selv - v0) : 0.0f;
        float Z = e;
#pragma unroll
        for (int off = 32; off >= 1; off >>= 1) Z += __shfl_xor(Z, off);
        if (lane < 16) { wts[w + 4][lane] = e / Z; jidx[w + 4][lane] = selj; }
    }
    if (w == 3) {  // avg-over-heads top-16 (mean scale is monotone -> skip)
        float va[16];
#pragma unroll
        for (int r = 0; r < 16; ++r) {
            const int j = lane + r * 64;
            va[r] = (pavg[0][j] + pavg[1][j]) + (pavg[2][j] + pavg[3][j]);
        }
        float selv; int selj;
        wave_topk16(va, lane, selv, selj);
        if (lane < 16) aidx[lane] = selj;
    }
    __syncthreads();

#pragma unroll
    for (int rr = 0; rr < 2; ++rr) {
        const int p = tid + rr * 256;
        const int h = p >> 6, d = p & 63;
        float o = 0.0f;
#pragma unroll
        for (int t = 0; t < 16; ++t)
            o = fmaf(wts[h][t], V[((size_t)(bl * C_ + jidx[h][t])) * DM_ + h * D_ + d], o);
        O[((size_t)(bl * C_ + i)) * DM_ + h * D_ + d] = o;
    }
    if (tid < 16) arow[aidx[tid]] = 1.0f;
    __syncthreads();
    *(float4*)(Aout + ((size_t)(b * C_ + i)) * C_ + tid * 4) = *(const float4*)(&arow[tid * 4]);
}

// ---- kernel 4: delta = O @ Wo^T + bo ; M_tilde = M + gate*delta (fp32 out), chunk-local ----
__global__ __launch_bounds__(256) void final_gemm(const float* __restrict__ O,
    const float* __restrict__ Wo, const float* __restrict__ Mi,
    const float* __restrict__ bo, const float* __restrict__ gatep,
    float* __restrict__ out)
{
    __shared__ float smem[2 * BKT * LDT];
    const int row0 = blockIdx.x * BM, col0 = blockIdx.y * BN;
    float acc[8][8] = {};
    sgemm_tile(O, Wo, DM_, DM_, DM_, row0, col0, smem, smem + BKT * LDT, acc);
    const float g = gatep[0];
    const int ty4 = (threadIdx.x >> 4) << 2;
    const int tx4 = (threadIdx.x & 15) << 2;
#pragma unroll
    for (int r = 0; r < 8; ++r) {
        const int gr = row0 + row_of(r, ty4);
#pragma unroll
        for (int hf = 0; hf < 2; ++hf) {
            const int col = col0 + hf * 64 + tx4;
            const float4 mrow = *(const float4*)(Mi + (size_t)gr * NP_ + col);
            const float4 bo4  = *(const float4*)(bo + col);
            float4 o4;
            o4.x = mrow.x + g * (acc[r][hf * 4 + 0] + bo4.x);
            o4.y = mrow.y + g * (acc[r][hf * 4 + 1] + bo4.y);
            o4.z = mrow.z + g * (acc[r][hf * 4 + 2] + bo4.z);
            o4.w = mrow.w + g * (acc[r][hf * 4 + 3] + bo4.w);
            *(float4*)(out + (size_t)gr * NP_ + col) = o4;
        }
    }
}

extern "C" void kernel_launch(void* const* d_in, const int* in_sizes, int n_in,
                              void* d_out, int out_size, void* d_ws, size_t ws_size,
                              hipStream_t stream)
{
    (void)in_sizes; (void)n_in; (void)out_size;
    const float* Mi   = (const float*)d_in[0];
    const float* Wq   = (const float*)d_in[1];
    const float* Wk   = (const float*)d_in[2];
    const float* Wv   = (const float*)d_in[3];
    const float* Wo   = (const float*)d_in[4];
    const float* bo   = (const float*)d_in[5];
    const float* gate = (const float*)d_in[6];
    float* out  = (float*)d_out;                       // fp32: reference outputs are float32
    float* Aout = out + (size_t)BC_ * NP_;

    // Workspace-adaptive batch chunking.
    // Per-batch floats: Q + K + V (O aliases Q) + S(8 heads):
    const size_t per_b = (size_t)3 * C_ * DM_ + (size_t)H_ * C_ * C_;  // ~38 MiB/batch
    const size_t ws_floats = ws_size / 4;
    int NB = (int)(ws_floats / per_b);
    if (NB < 1) NB = 1;
    if (NB > B_) NB = B_;

    float* ws = (float*)d_ws;
    float* Qc = ws;                                // NB*C*DM floats; doubles as O after score_gemm
    float* Kc = Qc + (size_t)NB * C_ * DM_;
    float* Vc = Kc + (size_t)NB * C_ * DM_;
    float* Sc = Vc + (size_t)NB * C_ * DM_;        // NB*H*C*C floats

    for (int b0 = 0; b0 < B_; b0 += NB) {
        const int nb = (B_ - b0 < NB) ? (B_ - b0) : NB;
        const float* Mi_c = Mi + (size_t)b0 * C_ * NP_;
        qkv_gemm<<<dim3(nb * C_ / BM, DM_ / BN, 3), 256, 0, stream>>>(Mi_c, Wq, Wk, Wv, Qc, Kc, Vc);
        score_gemm<<<dim3(C_ / BM, C_ / BN, nb * 8), 256, 0, stream>>>(Qc, Kc, Sc);
        topk_attn<<<dim3(nb * C_), 256, 0, stream>>>(Sc, Vc, Qc /*O*/, Aout, b0);
        final_gemm<<<dim3(nb * C_ / BM, NP_ / BN, 1), 256, 0, stream>>>(
            Qc /*O*/, Wo, Mi_c, bo, gate, out + (size_t)b0 * C_ * NP_);
    }
}